// Round 1
// baseline (134.797 us; speedup 1.0000x reference)
//
#include <hip/hip_runtime.h>
#include <hip/hip_bf16.h>
#include <math.h>

#define Bb 8
#define Lq 1024
#define Pp 512   // = O
#define Dd 32
#define Kk 8
#define Mm 512
#define EPSf 1e-5f

__device__ __forceinline__ float tanh_fast(float x) {
    float cx = fminf(10.0f, fmaxf(-10.0f, x));
    float e2 = __expf(2.0f * cx);
    return 1.0f - 2.0f * __builtin_amdgcn_rcpf(e2 + 1.0f);
}

// ---------------- Kernel 1: scores -> gn -> tanh -> V -> n1 -> xr ----------------
// grid = B*D*2 (512), block = 256. Each block: one (b,d), half of the p range.
__global__ __launch_bounds__(256) void k1_scores_v(
    const float* __restrict__ x, const float* __restrict__ xd,
    const float* __restrict__ yd,
    const float* __restrict__ gng, const float* __restrict__ gnb,
    const float* __restrict__ gnm, const float* __restrict__ gnv,
    const float* __restrict__ n1g, const float* __restrict__ n1b,
    const float* __restrict__ n1m, const float* __restrict__ n1v,
    float* __restrict__ xr)
{
    __shared__ float xd_s[Lq][Kk];   // 32 KB
    __shared__ float w_s[Lq];        // 4 KB

    int bid = blockIdx.x;
    int ph = bid & 1;
    int d  = (bid >> 1) & (Dd - 1);
    int b  = bid >> 6;
    int tid = threadIdx.x;

    // stage x_date[b, :, d, :] rows (8 consecutive floats per l) and x[b, :, d]
    const float* xd_base = xd + ((size_t)b * Lq * Dd + d) * Kk;
    for (int l = tid; l < Lq; l += 256) {
        const float4* src = (const float4*)(xd_base + (size_t)l * Dd * Kk);
        ((float4*)xd_s[l])[0] = src[0];
        ((float4*)xd_s[l])[1] = src[1];
        w_s[l] = x[((size_t)b * Lq + l) * Dd + d];
    }

    // per-thread y_date row (p fixed per thread)
    int p = ph * 256 + tid;
    const float* yd_base = yd + (((size_t)b * Pp + p) * Dd + d) * Kk;
    float4 y0 = ((const float4*)yd_base)[0];
    float4 y1 = ((const float4*)yd_base)[1];
    float ydr[Kk] = {y0.x, y0.y, y0.z, y0.w, y1.x, y1.y, y1.z, y1.w};

    float inv_g  = gng[d] * rsqrtf(gnv[d] + EPSf);
    float bias_g = gnb[d] - gnm[d] * inv_g;

    __syncthreads();

    float acc = 0.0f;
    #pragma unroll 8
    for (int l = 0; l < Lq; ++l) {
        float s = xd_s[l][0] * ydr[0];
        #pragma unroll
        for (int k = 1; k < Kk; ++k) s = fmaf(xd_s[l][k], ydr[k], s);
        float t = tanh_fast(fmaf(s, inv_g, bias_g));
        acc = fmaf(w_s[l], t, acc);
    }

    float inv1 = n1g[d] * rsqrtf(n1v[d] + EPSf);
    float bs1  = n1b[d] - n1m[d] * inv1;
    xr[((size_t)b * Dd + d) * Pp + p] = fmaf(acc, inv1, bs1);
}

// ---------------- Kernel 2a: y1 = gelu(W1 @ xr + b1) ----------------
// grid = B * (M/16) * (P/256) = 512, block = 256
__global__ __launch_bounds__(256) void k2_ffn1(
    const float* __restrict__ xr, const float* __restrict__ w1,
    const float* __restrict__ b1, float* __restrict__ y1)
{
    __shared__ float xr_s[Dd][256];   // 32 KB
    int bid = blockIdx.x;
    int pt = bid & 1;
    int mt = (bid >> 1) & 31;
    int b  = bid >> 6;
    int tid = threadIdx.x;
    int p = pt * 256 + tid;

    for (int d = 0; d < Dd; ++d)
        xr_s[d][tid] = xr[((size_t)b * Dd + d) * Pp + p];
    __syncthreads();

    #pragma unroll
    for (int mi = 0; mi < 16; ++mi) {
        int m = mt * 16 + mi;
        float acc = b1[m];
        #pragma unroll
        for (int d = 0; d < Dd; ++d)
            acc = fmaf(w1[m * Dd + d], xr_s[d][tid], acc);
        float g = 0.5f * acc * (1.0f + erff(acc * 0.70710678118654752f));
        y1[((size_t)b * Mm + m) * Pp + p] = g;
    }
}

// ---------------- Kernel 2b: out = n2(xr + W2 @ y1 + b2), transposed store ----------------
// grid = B * (P/16) = 256, block = 512 (lanes: d = tid&31 fast, pl = tid>>5)
__global__ __launch_bounds__(512) void k3_ffn2(
    const float* __restrict__ xr, const float* __restrict__ y1,
    const float* __restrict__ w2, const float* __restrict__ b2,
    const float* __restrict__ n2g, const float* __restrict__ n2b,
    const float* __restrict__ n2m, const float* __restrict__ n2v,
    float* __restrict__ out)
{
    __shared__ float w2t[Mm][Dd];    // 64 KB, [m][d] so lane-consecutive d reads are conflict-free
    int bid = blockIdx.x;
    int pt = bid & 31;
    int b  = bid >> 5;
    int tid = threadIdx.x;

    for (int i = tid; i < Mm * Dd; i += 512) {
        int d = i & (Dd - 1);
        int m = i >> 5;
        w2t[m][d] = w2[d * Mm + m];
    }
    __syncthreads();

    int d  = tid & (Dd - 1);
    int pl = tid >> 5;           // 0..15
    int p  = pt * 16 + pl;

    const float* y1p = y1 + (size_t)b * Mm * Pp + p;
    float acc = 0.0f;
    #pragma unroll 8
    for (int m = 0; m < Mm; ++m)
        acc = fmaf(w2t[m][d], y1p[(size_t)m * Pp], acc);

    float inv2 = n2g[d] * rsqrtf(n2v[d] + EPSf);
    float bs2  = n2b[d] - n2m[d] * inv2;
    float xrv  = xr[((size_t)b * Dd + d) * Pp + p];
    float v    = xrv + acc + b2[d];
    out[((size_t)b * Pp + p) * Dd + d] = fmaf(v, inv2, bs2);
}

extern "C" void kernel_launch(void* const* d_in, const int* in_sizes, int n_in,
                              void* d_out, int out_size, void* d_ws, size_t ws_size,
                              hipStream_t stream) {
    const float* x    = (const float*)d_in[0];
    const float* xd   = (const float*)d_in[1];
    const float* yd   = (const float*)d_in[2];
    const float* gng  = (const float*)d_in[3];
    const float* gnb  = (const float*)d_in[4];
    const float* gnm  = (const float*)d_in[5];
    const float* gnv  = (const float*)d_in[6];
    const float* n1g  = (const float*)d_in[7];
    const float* n1b  = (const float*)d_in[8];
    const float* n1m  = (const float*)d_in[9];
    const float* n1v  = (const float*)d_in[10];
    const float* w1   = (const float*)d_in[11];
    const float* b1   = (const float*)d_in[12];
    const float* w2   = (const float*)d_in[13];
    const float* b2   = (const float*)d_in[14];
    const float* n2g  = (const float*)d_in[15];
    const float* n2b  = (const float*)d_in[16];
    const float* n2m  = (const float*)d_in[17];
    const float* n2v  = (const float*)d_in[18];

    float* xr = (float*)d_ws;                                        // B*D*P f32 = 512 KB
    float* y1 = (float*)((char*)d_ws + (size_t)Bb * Dd * Pp * 4);    // B*M*P f32 = 8 MB

    float* outf = (float*)d_out;

    k1_scores_v<<<Bb * Dd * 2, 256, 0, stream>>>(
        x, xd, yd, gng, gnb, gnm, gnv, n1g, n1b, n1m, n1v, xr);
    k2_ffn1<<<Bb * 32 * 2, 256, 0, stream>>>(xr, w1, b1, y1);
    k3_ffn2<<<Bb * 32, 512, 0, stream>>>(xr, y1, w2, b2, n2g, n2b, n2m, n2v, outf);
}

// Round 2
// 73.853 us; speedup vs baseline: 1.8252x; 1.8252x over previous
//
#include <hip/hip_runtime.h>
#include <hip/hip_bf16.h>
#include <math.h>

#define Bb 8
#define Lq 1024
#define Pp 512   // = O
#define Dd 32
#define Kk 8
#define Mm 512
#define EPSf 1e-5f
#define TWO_LOG2E 2.885390081777927f   // 2*log2(e)

typedef float f32x16 __attribute__((ext_vector_type(16)));
typedef short s16x8  __attribute__((ext_vector_type(8)));

__device__ __forceinline__ ushort f2bf(float f) {
    union { float f; unsigned u; } v; v.f = f;
    unsigned r = (v.u + 0x7FFFu + ((v.u >> 16) & 1u)) >> 16;  // RNE
    return (ushort)r;
}

// ---------------- Kernel 1: scores(MFMA) -> tanh -> V -> n1 -> xr ----------------
// grid = B*D = 256 blocks, 256 threads (4 waves). Wave w owns p in [w*128, w*128+128).
// D[p,l] tile = mfma_32x32x16( A=yd[p,k], B=xd_scaled[k,l] ), bias in k=8 slot.
// tanh(z) = 1 - 2/(exp2(z')+1) with z' = 2*log2e*(inv_g*s + bias_g) folded into A/B.
__global__ __launch_bounds__(256) void k1_scores_v(
    const float* __restrict__ x, const float* __restrict__ xd,
    const float* __restrict__ yd,
    const float* __restrict__ gng, const float* __restrict__ gnb,
    const float* __restrict__ gnm, const float* __restrict__ gnv,
    const float* __restrict__ n1g, const float* __restrict__ n1b,
    const float* __restrict__ n1m, const float* __restrict__ n1v,
    float* __restrict__ xrw)
{
    __shared__ __align__(16) ushort xd_s[Lq][8];   // bf16, pre-scaled, 16 KB
    __shared__ float w_s[Lq];                      // 4 KB
    __shared__ float wred[4];

    int b = blockIdx.x >> 5;
    int d = blockIdx.x & 31;
    int tid  = threadIdx.x;
    int lane = tid & 63;
    int wid  = tid >> 6;
    int lo   = lane & 31;
    int hi   = lane >> 5;

    float inv_g = gng[d] * rsqrtf(gnv[d] + EPSf);
    float cs    = TWO_LOG2E * inv_g;
    float biasp = TWO_LOG2E * (gnb[d] - gnm[d] * inv_g);

    // stage xd[b,:,d,:] scaled->bf16, and w = x[b,:,d]
    const float* xdb = xd + (size_t)b * (Lq * Dd * Kk) + (size_t)d * Kk;
    float wsum = 0.f;
    for (int l = tid; l < Lq; l += 256) {
        const float* row = xdb + (size_t)l * (Dd * Kk);
        float4 a0 = ((const float4*)row)[0];
        float4 a1 = ((const float4*)row)[1];
        s16x8 rv;
        rv[0] = (short)f2bf(a0.x * cs); rv[1] = (short)f2bf(a0.y * cs);
        rv[2] = (short)f2bf(a0.z * cs); rv[3] = (short)f2bf(a0.w * cs);
        rv[4] = (short)f2bf(a1.x * cs); rv[5] = (short)f2bf(a1.y * cs);
        rv[6] = (short)f2bf(a1.z * cs); rv[7] = (short)f2bf(a1.w * cs);
        *((s16x8*)xd_s[l]) = rv;
        float w = x[((size_t)b * Lq + l) * Dd + d];
        w_s[l] = w;
        wsum += w;
    }
    #pragma unroll
    for (int m = 1; m < 64; m <<= 1) wsum += __shfl_xor(wsum, m);
    if (lane == 0) wred[wid] = wsum;
    __syncthreads();
    float S_w = wred[0] + wred[1] + wred[2] + wred[3];

    // A-frags (yd), hoisted: lanes 0-31 carry k=0..7 data, lanes 32-63 carry {1.0, 0..}
    s16x8 afr[4];
    #pragma unroll
    for (int nt = 0; nt < 4; ++nt) {
        s16x8 v = {};
        if (hi == 0) {
            int p = wid * 128 + nt * 32 + lo;
            const float* yr = yd + ((size_t)(b * Pp + p) * Dd + d) * Kk;
            float4 y0 = ((const float4*)yr)[0];
            float4 y1 = ((const float4*)yr)[1];
            v[0] = (short)f2bf(y0.x); v[1] = (short)f2bf(y0.y);
            v[2] = (short)f2bf(y0.z); v[3] = (short)f2bf(y0.w);
            v[4] = (short)f2bf(y1.x); v[5] = (short)f2bf(y1.y);
            v[6] = (short)f2bf(y1.z); v[7] = (short)f2bf(y1.w);
        } else {
            v[0] = (short)0x3F80;   // bf16 1.0 at k=8
        }
        afr[nt] = v;
    }
    s16x8 bconst = {};
    bconst[0] = (short)f2bf(biasp); // bias at k=8

    float accr[4][16];
    #pragma unroll
    for (int nt = 0; nt < 4; ++nt)
        #pragma unroll
        for (int r = 0; r < 16; ++r) accr[nt][r] = 0.f;

    for (int lt = 0; lt < Lq / 32; ++lt) {
        s16x8 bfr;
        if (hi == 0) bfr = *((const s16x8*)xd_s[lt * 32 + lo]);
        else         bfr = bconst;
        float wl = w_s[lt * 32 + lo];
        #pragma unroll
        for (int nt = 0; nt < 4; ++nt) {
            f32x16 z = {};
            f32x16 dd = __builtin_amdgcn_mfma_f32_32x32x16_bf16(afr[nt], bfr, z, 0, 0, 0);
            #pragma unroll
            for (int r = 0; r < 16; ++r) {
                float e  = __builtin_amdgcn_exp2f(dd[r]);
                float rc = __builtin_amdgcn_rcpf(e + 1.0f);
                accr[nt][r] = fmaf(wl, rc, accr[nt][r]);
            }
        }
    }

    float inv1 = n1g[d] * rsqrtf(n1v[d] + EPSf);
    float bs1  = n1b[d] - n1m[d] * inv1;
    #pragma unroll
    for (int nt = 0; nt < 4; ++nt) {
        #pragma unroll
        for (int r = 0; r < 16; ++r) {
            float v = accr[nt][r];
            v += __shfl_xor(v, 1);
            v += __shfl_xor(v, 2);
            v += __shfl_xor(v, 4);
            v += __shfl_xor(v, 8);
            v += __shfl_xor(v, 16);
            if (lo == 0) {
                int p = wid * 128 + nt * 32 + (r & 3) + ((r >> 2) << 3) + (hi << 2);
                float V = S_w - 2.0f * v;
                xrw[((size_t)(b * Dd + d)) * Pp + p] = fmaf(V, inv1, bs1);
            }
        }
    }
}

// ---------------- Kernel 2: fused FFN: h=gelu(W1@xr+b1); out=n2(xr+W2@h+b2), transposed store
// grid = B * (P/16) = 256 blocks, 256 threads. h kept in LDS p-major (padded).
__device__ __forceinline__ float gelu_t(float x) {
    // 0.5*x*(1+tanh(.79788456*(x+.044715x^3))) = x*(1 - 1/(exp2(u')+1))
    float x2 = x * x;
    float up = x * fmaf(x2, 0.10294387f, 2.3022118f);  // 2*log2e*0.79788456*(1, 0.044715)
    float e  = __builtin_amdgcn_exp2f(up);
    float rc = __builtin_amdgcn_rcpf(e + 1.0f);
    return x * (1.0f - rc);
}

#define HPAD 516

__global__ __launch_bounds__(256) void k2_ffn(
    const float* __restrict__ xr, const float* __restrict__ w1,
    const float* __restrict__ b1, const float* __restrict__ w2,
    const float* __restrict__ b2,
    const float* __restrict__ n2g, const float* __restrict__ n2b,
    const float* __restrict__ n2m, const float* __restrict__ n2v,
    float* __restrict__ out)
{
    __shared__ float xr_s[Dd][16];        // 2 KB
    __shared__ float h_s[16][HPAD];       // 33 KB, p-major, pad->2-way-free banks

    int b  = blockIdx.x >> 5;
    int p0 = (blockIdx.x & 31) * 16;
    int tid = threadIdx.x;

    // phase 1: stage xr tile
    for (int i = tid; i < Dd * 16; i += 256) {
        int d = i >> 4, pl = i & 15;
        xr_s[d][pl] = xr[((size_t)(b * Dd + d)) * Pp + p0 + pl];
    }
    __syncthreads();

    // phase 2: h[m, p-tile] for m = tid, tid+256
    #pragma unroll
    for (int mi = 0; mi < 2; ++mi) {
        int m = tid + mi * 256;
        const float* w1r = w1 + (size_t)m * Dd;
        float4 wq[8];
        #pragma unroll
        for (int j = 0; j < 8; ++j) wq[j] = ((const float4*)w1r)[j];
        float acc[16];
        float bm = b1[m];
        #pragma unroll
        for (int p = 0; p < 16; ++p) acc[p] = bm;
        #pragma unroll
        for (int d8 = 0; d8 < 8; ++d8) {
            #pragma unroll
            for (int j = 0; j < 4; ++j) {
                int d = d8 * 4 + j;
                float w = (j == 0) ? wq[d8].x : (j == 1) ? wq[d8].y : (j == 2) ? wq[d8].z : wq[d8].w;
                float4 xv0 = *(const float4*)&xr_s[d][0];
                float4 xv1 = *(const float4*)&xr_s[d][4];
                float4 xv2 = *(const float4*)&xr_s[d][8];
                float4 xv3 = *(const float4*)&xr_s[d][12];
                acc[0]  = fmaf(w, xv0.x, acc[0]);  acc[1]  = fmaf(w, xv0.y, acc[1]);
                acc[2]  = fmaf(w, xv0.z, acc[2]);  acc[3]  = fmaf(w, xv0.w, acc[3]);
                acc[4]  = fmaf(w, xv1.x, acc[4]);  acc[5]  = fmaf(w, xv1.y, acc[5]);
                acc[6]  = fmaf(w, xv1.z, acc[6]);  acc[7]  = fmaf(w, xv1.w, acc[7]);
                acc[8]  = fmaf(w, xv2.x, acc[8]);  acc[9]  = fmaf(w, xv2.y, acc[9]);
                acc[10] = fmaf(w, xv2.z, acc[10]); acc[11] = fmaf(w, xv2.w, acc[11]);
                acc[12] = fmaf(w, xv3.x, acc[12]); acc[13] = fmaf(w, xv3.y, acc[13]);
                acc[14] = fmaf(w, xv3.z, acc[14]); acc[15] = fmaf(w, xv3.w, acc[15]);
            }
        }
        #pragma unroll
        for (int p = 0; p < 16; ++p) h_s[p][m] = gelu_t(acc[p]);
    }
    __syncthreads();

    // phase 3: out[d, p-tile] = n2(xr + W2 @ h + b2), store transposed [B,P,D]
    int pl = tid & 15;
    int d0 = tid >> 4;   // 0..15
    #pragma unroll
    for (int q = 0; q < 2; ++q) {
        int d = d0 + 16 * q;
        const float* w2r = w2 + (size_t)d * Mm;
        float acc2 = 0.f;
        #pragma unroll 8
        for (int m4 = 0; m4 < Mm / 4; ++m4) {
            float4 hv = *(const float4*)&h_s[pl][m4 * 4];
            float4 wv = ((const float4*)w2r)[m4];
            acc2 = fmaf(hv.x, wv.x, acc2);
            acc2 = fmaf(hv.y, wv.y, acc2);
            acc2 = fmaf(hv.z, wv.z, acc2);
            acc2 = fmaf(hv.w, wv.w, acc2);
        }
        float inv2 = n2g[d] * rsqrtf(n2v[d] + EPSf);
        float bs2  = n2b[d] - n2m[d] * inv2;
        float vv   = xr_s[d][pl] + acc2 + b2[d];
        out[((size_t)(b * Pp + p0 + pl)) * Dd + d] = fmaf(vv, inv2, bs2);
    }
}

extern "C" void kernel_launch(void* const* d_in, const int* in_sizes, int n_in,
                              void* d_out, int out_size, void* d_ws, size_t ws_size,
                              hipStream_t stream) {
    const float* x    = (const float*)d_in[0];
    const float* xd   = (const float*)d_in[1];
    const float* yd   = (const float*)d_in[2];
    const float* gng  = (const float*)d_in[3];
    const float* gnb  = (const float*)d_in[4];
    const float* gnm  = (const float*)d_in[5];
    const float* gnv  = (const float*)d_in[6];
    const float* n1g  = (const float*)d_in[7];
    const float* n1b  = (const float*)d_in[8];
    const float* n1m  = (const float*)d_in[9];
    const float* n1v  = (const float*)d_in[10];
    const float* w1   = (const float*)d_in[11];
    const float* b1   = (const float*)d_in[12];
    const float* w2   = (const float*)d_in[13];
    const float* b2   = (const float*)d_in[14];
    const float* n2g  = (const float*)d_in[15];
    const float* n2b  = (const float*)d_in[16];
    const float* n2m  = (const float*)d_in[17];
    const float* n2v  = (const float*)d_in[18];

    float* xr   = (float*)d_ws;        // B*D*P f32 = 512 KB
    float* outf = (float*)d_out;

    k1_scores_v<<<Bb * Dd, 256, 0, stream>>>(
        x, xd, yd, gng, gnb, gnm, gnv, n1g, n1b, n1m, n1v, xr);
    k2_ffn<<<Bb * (Pp / 16), 256, 0, stream>>>(
        xr, w1, b1, w2, b2, n2g, n2b, n2m, n2v, outf);
}

// Round 3
// 63.846 us; speedup vs baseline: 2.1113x; 1.1567x over previous
//
#include <hip/hip_runtime.h>
#include <hip/hip_bf16.h>
#include <math.h>

#define Bb 8
#define Lq 1024
#define Pp 512   // = O
#define Dd 32
#define Kk 8
#define Mm 512
#define EPSf 1e-5f
#define TWO_LOG2E 2.885390081777927f   // 2*log2(e)

#define SPLIT 4
#define CHUNK (Lq / SPLIT)   // 256

typedef float f32x16 __attribute__((ext_vector_type(16)));
typedef short s16x8  __attribute__((ext_vector_type(8)));

__device__ __forceinline__ ushort f2bf(float f) {
    union { float f; unsigned u; } v; v.f = f;
    unsigned r = (v.u + 0x7FFFu + ((v.u >> 16) & 1u)) >> 16;  // RNE
    return (ushort)r;
}

// ---------------- Kernel 1: partial scores(MFMA) -> tanh -> partial V ----------------
// grid = B*D*SPLIT = 1024 blocks, 256 threads (4 waves). Block owns an L-chunk of 256.
// Wave w owns p in [w*128, w*128+128). Writes V_part = Sw_part - 2*sum(w*rc) to ws.
__global__ __launch_bounds__(256) void k1_scores_v(
    const float* __restrict__ x, const float* __restrict__ xd,
    const float* __restrict__ yd,
    const float* __restrict__ gng, const float* __restrict__ gnb,
    const float* __restrict__ gnm, const float* __restrict__ gnv,
    float* __restrict__ vpart)
{
    __shared__ __align__(16) ushort xd_s[CHUNK][8];   // bf16, pre-scaled, 4 KB
    __shared__ float w_s[CHUNK];                      // 1 KB
    __shared__ float wred[4];

    int s = blockIdx.x & (SPLIT - 1);
    int d = (blockIdx.x >> 2) & 31;
    int b = blockIdx.x >> 7;
    int tid  = threadIdx.x;
    int lane = tid & 63;
    int wid  = tid >> 6;
    int lo   = lane & 31;
    int hi   = lane >> 5;

    float inv_g = gng[d] * rsqrtf(gnv[d] + EPSf);
    float cs    = TWO_LOG2E * inv_g;
    float biasp = TWO_LOG2E * (gnb[d] - gnm[d] * inv_g);

    // stage xd[b, s*CHUNK + tid, d, :] scaled->bf16, and w = x[b, l, d]
    int lg = s * CHUNK + tid;
    const float* row = xd + ((size_t)(b * Lq + lg) * Dd + d) * Kk;
    float4 a0 = ((const float4*)row)[0];
    float4 a1 = ((const float4*)row)[1];
    s16x8 rv;
    rv[0] = (short)f2bf(a0.x * cs); rv[1] = (short)f2bf(a0.y * cs);
    rv[2] = (short)f2bf(a0.z * cs); rv[3] = (short)f2bf(a0.w * cs);
    rv[4] = (short)f2bf(a1.x * cs); rv[5] = (short)f2bf(a1.y * cs);
    rv[6] = (short)f2bf(a1.z * cs); rv[7] = (short)f2bf(a1.w * cs);
    *((s16x8*)xd_s[tid]) = rv;
    float w = x[((size_t)(b * Lq + lg)) * Dd + d];
    w_s[tid] = w;

    float wsum = w;
    #pragma unroll
    for (int m = 1; m < 64; m <<= 1) wsum += __shfl_xor(wsum, m);
    if (lane == 0) wred[wid] = wsum;

    // A-frags (yd), hoisted: lanes 0-31 carry k=0..7 data, lanes 32-63 carry {1.0, 0..}
    s16x8 afr[4];
    #pragma unroll
    for (int nt = 0; nt < 4; ++nt) {
        s16x8 v = {};
        if (hi == 0) {
            int p = wid * 128 + nt * 32 + lo;
            const float* yr = yd + ((size_t)(b * Pp + p) * Dd + d) * Kk;
            float4 y0 = ((const float4*)yr)[0];
            float4 y1 = ((const float4*)yr)[1];
            v[0] = (short)f2bf(y0.x); v[1] = (short)f2bf(y0.y);
            v[2] = (short)f2bf(y0.z); v[3] = (short)f2bf(y0.w);
            v[4] = (short)f2bf(y1.x); v[5] = (short)f2bf(y1.y);
            v[6] = (short)f2bf(y1.z); v[7] = (short)f2bf(y1.w);
        } else {
            v[0] = (short)0x3F80;   // bf16 1.0 at k=8
        }
        afr[nt] = v;
    }
    s16x8 bconst = {};
    bconst[0] = (short)f2bf(biasp); // bias at k=8

    __syncthreads();
    float S_w = wred[0] + wred[1] + wred[2] + wred[3];

    float accr[4][16];
    #pragma unroll
    for (int nt = 0; nt < 4; ++nt)
        #pragma unroll
        for (int r = 0; r < 16; ++r) accr[nt][r] = 0.f;

    for (int lt = 0; lt < CHUNK / 32; ++lt) {
        s16x8 bfr;
        if (hi == 0) bfr = *((const s16x8*)xd_s[lt * 32 + lo]);
        else         bfr = bconst;
        float wl = w_s[lt * 32 + lo];
        #pragma unroll
        for (int nt = 0; nt < 4; ++nt) {
            f32x16 z = {};
            f32x16 dd = __builtin_amdgcn_mfma_f32_32x32x16_bf16(afr[nt], bfr, z, 0, 0, 0);
            #pragma unroll
            for (int r = 0; r < 16; ++r) {
                float e  = __builtin_amdgcn_exp2f(dd[r]);
                float rc = __builtin_amdgcn_rcpf(e + 1.0f);
                accr[nt][r] = fmaf(wl, rc, accr[nt][r]);
            }
        }
    }

    #pragma unroll
    for (int nt = 0; nt < 4; ++nt) {
        #pragma unroll
        for (int r = 0; r < 16; ++r) {
            float v = accr[nt][r];
            v += __shfl_xor(v, 1);
            v += __shfl_xor(v, 2);
            v += __shfl_xor(v, 4);
            v += __shfl_xor(v, 8);
            v += __shfl_xor(v, 16);
            if (lo == 0) {
                int p = wid * 128 + nt * 32 + (r & 3) + ((r >> 2) << 3) + (hi << 2);
                vpart[(((size_t)s * Bb + b) * Dd + d) * Pp + p] = S_w - 2.0f * v;
            }
        }
    }
}

// ---------------- Kernel 2: reduce partials -> n1 -> xr; fused FFN; n2; transposed store
// grid = B * (P/16) = 256 blocks, 512 threads (8 waves).
__device__ __forceinline__ float gelu_t(float x) {
    // tanh-form GELU via exp2: x*(1 - 1/(exp2(u')+1))
    float x2 = x * x;
    float up = x * fmaf(x2, 0.10294387f, 2.3022118f);  // 2*log2e*0.79788456*(1, 0.044715)
    float e  = __builtin_amdgcn_exp2f(up);
    float rc = __builtin_amdgcn_rcpf(e + 1.0f);
    return x * (1.0f - rc);
}

#define HPAD 516

__global__ __launch_bounds__(512) void k2_ffn(
    const float* __restrict__ vpart,
    const float* __restrict__ n1g, const float* __restrict__ n1b,
    const float* __restrict__ n1m, const float* __restrict__ n1v,
    const float* __restrict__ w1, const float* __restrict__ b1,
    const float* __restrict__ w2, const float* __restrict__ b2,
    const float* __restrict__ n2g, const float* __restrict__ n2b,
    const float* __restrict__ n2m, const float* __restrict__ n2v,
    float* __restrict__ out)
{
    __shared__ float xr_s[Dd][16];        // 2 KB
    __shared__ float h_s[16][HPAD];       // 33 KB, p-major, pad->2-way-free banks

    int b  = blockIdx.x >> 5;
    int p0 = (blockIdx.x & 31) * 16;
    int tid = threadIdx.x;

    // phase 1: reduce 4 partials, apply n1 affine -> xr tile (one thread per (d,pl))
    {
        int d  = tid >> 4;
        int pl = tid & 15;
        size_t base = ((size_t)b * Dd + d) * Pp + p0 + pl;
        float v = vpart[base] + vpart[base + (size_t)Bb * Dd * Pp]
                + vpart[base + 2 * (size_t)Bb * Dd * Pp] + vpart[base + 3 * (size_t)Bb * Dd * Pp];
        float inv1 = n1g[d] * rsqrtf(n1v[d] + EPSf);
        float bs1  = n1b[d] - n1m[d] * inv1;
        xr_s[d][pl] = fmaf(v, inv1, bs1);
    }
    __syncthreads();

    // phase 2: h[m, p-tile], one m per thread
    {
        int m = tid;
        const float* w1r = w1 + (size_t)m * Dd;
        float4 wq[8];
        #pragma unroll
        for (int j = 0; j < 8; ++j) wq[j] = ((const float4*)w1r)[j];
        float acc[16];
        float bm = b1[m];
        #pragma unroll
        for (int p = 0; p < 16; ++p) acc[p] = bm;
        #pragma unroll
        for (int d8 = 0; d8 < 8; ++d8) {
            #pragma unroll
            for (int j = 0; j < 4; ++j) {
                int d = d8 * 4 + j;
                float w = (j == 0) ? wq[d8].x : (j == 1) ? wq[d8].y : (j == 2) ? wq[d8].z : wq[d8].w;
                float4 xv0 = *(const float4*)&xr_s[d][0];
                float4 xv1 = *(const float4*)&xr_s[d][4];
                float4 xv2 = *(const float4*)&xr_s[d][8];
                float4 xv3 = *(const float4*)&xr_s[d][12];
                acc[0]  = fmaf(w, xv0.x, acc[0]);  acc[1]  = fmaf(w, xv0.y, acc[1]);
                acc[2]  = fmaf(w, xv0.z, acc[2]);  acc[3]  = fmaf(w, xv0.w, acc[3]);
                acc[4]  = fmaf(w, xv1.x, acc[4]);  acc[5]  = fmaf(w, xv1.y, acc[5]);
                acc[6]  = fmaf(w, xv1.z, acc[6]);  acc[7]  = fmaf(w, xv1.w, acc[7]);
                acc[8]  = fmaf(w, xv2.x, acc[8]);  acc[9]  = fmaf(w, xv2.y, acc[9]);
                acc[10] = fmaf(w, xv2.z, acc[10]); acc[11] = fmaf(w, xv2.w, acc[11]);
                acc[12] = fmaf(w, xv3.x, acc[12]); acc[13] = fmaf(w, xv3.y, acc[13]);
                acc[14] = fmaf(w, xv3.z, acc[14]); acc[15] = fmaf(w, xv3.w, acc[15]);
            }
        }
        #pragma unroll
        for (int p = 0; p < 16; ++p) h_s[p][m] = gelu_t(acc[p]);
    }
    __syncthreads();

    // phase 3: out[d, p-tile] = n2(xr + W2 @ h + b2), one (pl,d) per thread, transposed store
    {
        int pl = tid & 15;
        int d  = tid >> 4;   // 0..31
        const float* w2r = w2 + (size_t)d * Mm;
        float acc2 = 0.f;
        #pragma unroll 8
        for (int m4 = 0; m4 < Mm / 4; ++m4) {
            float4 hv = *(const float4*)&h_s[pl][m4 * 4];
            float4 wv = ((const float4*)w2r)[m4];
            acc2 = fmaf(hv.x, wv.x, acc2);
            acc2 = fmaf(hv.y, wv.y, acc2);
            acc2 = fmaf(hv.z, wv.z, acc2);
            acc2 = fmaf(hv.w, wv.w, acc2);
        }
        float inv2 = n2g[d] * rsqrtf(n2v[d] + EPSf);
        float bs2  = n2b[d] - n2m[d] * inv2;
        float vv   = xr_s[d][pl] + acc2 + b2[d];
        out[((size_t)(b * Pp + p0 + pl)) * Dd + d] = fmaf(vv, inv2, bs2);
    }
}

extern "C" void kernel_launch(void* const* d_in, const int* in_sizes, int n_in,
                              void* d_out, int out_size, void* d_ws, size_t ws_size,
                              hipStream_t stream) {
    const float* x    = (const float*)d_in[0];
    const float* xd   = (const float*)d_in[1];
    const float* yd   = (const float*)d_in[2];
    const float* gng  = (const float*)d_in[3];
    const float* gnb  = (const float*)d_in[4];
    const float* gnm  = (const float*)d_in[5];
    const float* gnv  = (const float*)d_in[6];
    const float* n1g  = (const float*)d_in[7];
    const float* n1b  = (const float*)d_in[8];
    const float* n1m  = (const float*)d_in[9];
    const float* n1v  = (const float*)d_in[10];
    const float* w1   = (const float*)d_in[11];
    const float* b1   = (const float*)d_in[12];
    const float* w2   = (const float*)d_in[13];
    const float* b2   = (const float*)d_in[14];
    const float* n2g  = (const float*)d_in[15];
    const float* n2b  = (const float*)d_in[16];
    const float* n2m  = (const float*)d_in[17];
    const float* n2v  = (const float*)d_in[18];

    float* vpart = (float*)d_ws;   // SPLIT * B * D * P f32 = 2 MB
    float* outf  = (float*)d_out;

    k1_scores_v<<<Bb * Dd * SPLIT, 256, 0, stream>>>(
        x, xd, yd, gng, gnb, gnm, gnv, vpart);
    k2_ffn<<<Bb * (Pp / 16), 512, 0, stream>>>(
        vpart, n1g, n1b, n1m, n1v, w1, b1, w2, b2, n2g, n2b, n2m, n2v, outf);
}